// Round 1
// baseline (214.996 us; speedup 1.0000x reference)
//
#include <hip/hip_runtime.h>
#include <math.h>

#define DIAG 725
#define HALF 362.0f
#define NIMG 512
#define OFF 106
#define NANG 180

// One wave (64 lanes) per output element (angle a, sinogram row r).
// out[r*NANG + a] = sum_c bilinear(padded, rot_a(c, r))
// Padded image is zero outside the central 512x512 block, so we sample the
// raw input with bounds checks (exactly equivalent to the reference's
// clipped-index bilinear, since clipped taps always read zero pixels).
__global__ __launch_bounds__(256) void radon_kernel(
    const float* __restrict__ img, const float* __restrict__ angles,
    float* __restrict__ out, int n_ang)
{
    const int wave_in_blk = (int)(threadIdx.x >> 6);
    const int lane = (int)(threadIdx.x & 63);
    const int w = (int)blockIdx.x * 4 + wave_in_blk;   // global wave id
    const int a = w / DIAG;
    const int r = w - a * DIAG;
    if (a >= n_ang) return;

    const float ang = angles[a];
    const float rad = -ang * (float)(3.14159265358979323846 / 180.0);
    const float ct = cosf(rad);
    const float st = sinf(rad);

    const float dy = (float)r - HALF;
    // x_rot(c) = ct*c + Bx ; y_rot(c) = st*c + By   (padded coords)
    const float Bx = HALF - HALF * ct - st * dy;
    const float By = HALF - HALF * st + ct * dy;

    // Compute c-range where the 2x2 tap footprint can touch the data square
    // (padded coords (105, 618) exclusive; widen by 1 for safety).
    float lo = 0.0f, hi = 724.0f;
    if (fabsf(ct) > 1e-4f) {
        float c1 = (104.0f - Bx) / ct;
        float c2 = (619.0f - Bx) / ct;
        lo = fmaxf(lo, fminf(c1, c2));
        hi = fminf(hi, fmaxf(c1, c2));
    } else if (Bx < 103.0f || Bx > 620.0f) {
        hi = -1.0f;  // empty
    }
    if (fabsf(st) > 1e-4f) {
        float c1 = (104.0f - By) / st;
        float c2 = (619.0f - By) / st;
        lo = fmaxf(lo, fminf(c1, c2));
        hi = fminf(hi, fmaxf(c1, c2));
    } else if (By < 103.0f || By > 620.0f) {
        hi = -1.0f;  // empty
    }
    int clo = (int)fmaxf(0.0f, floorf(lo));
    int chi = (int)fminf(724.0f, ceilf(hi));

    float sum = 0.0f;
    for (int c = clo + lane; c <= chi; c += 64) {
        const float fc = (float)c;
        const float xr = fmaf(ct, fc, Bx);
        const float yr = fmaf(st, fc, By);
        const float fx = floorf(xr);
        const float fy = floorf(yr);
        const float ax = xr - fx;
        const float ay = yr - fy;
        const int xd = (int)fx - OFF;   // data coords
        const int yd = (int)fy - OFF;

        float Ia = 0.0f, Ib = 0.0f, Ic = 0.0f, Id = 0.0f;
        const bool x0v = (unsigned)xd < (unsigned)NIMG;
        const bool x1v = (unsigned)(xd + 1) < (unsigned)NIMG;
        if ((unsigned)yd < (unsigned)NIMG) {
            const float* row = img + yd * NIMG;
            if (x0v) Ia = row[xd];
            if (x1v) Ib = row[xd + 1];
        }
        if ((unsigned)(yd + 1) < (unsigned)NIMG) {
            const float* row = img + (yd + 1) * NIMG;
            if (x0v) Ic = row[xd];
            if (x1v) Id = row[xd + 1];
        }
        const float top = fmaf(ax, Ib - Ia, Ia);
        const float bot = fmaf(ax, Id - Ic, Ic);
        sum += fmaf(ay, bot - top, top);
    }

    // wave64 tree reduce
    #pragma unroll
    for (int off = 32; off > 0; off >>= 1)
        sum += __shfl_down(sum, off);

    if (lane == 0)
        out[r * n_ang + a] = sum;
}

extern "C" void kernel_launch(void* const* d_in, const int* in_sizes, int n_in,
                              void* d_out, int out_size, void* d_ws, size_t ws_size,
                              hipStream_t stream) {
    const float* img = (const float*)d_in[0];
    const float* angles = (const float*)d_in[1];
    float* out = (float*)d_out;
    const int n_ang = in_sizes[1];

    const int total_waves = n_ang * DIAG;           // 130500
    const int blocks = (total_waves + 3) / 4;       // 4 waves per 256-thread block
    radon_kernel<<<blocks, 256, 0, stream>>>(img, angles, out, n_ang);
}

// Round 2
// 137.172 us; speedup vs baseline: 1.5673x; 1.5673x over previous
//
#include <hip/hip_runtime.h>
#include <math.h>

#define DIAG 725
#define HALF 362.0f
#define NIMG 512
#define POFF 106          // data block offset inside padded image
#define PS   736          // padded row stride in floats (64B-aligned rows)
#define PI_F 3.14159265358979323846f

// ---------------- pad kernel: build 725x725 padded image (stride 736) -------
__global__ __launch_bounds__(256) void pad_kernel(const float* __restrict__ img,
                                                  float* __restrict__ pad)
{
    const int col = blockIdx.x * 256 + threadIdx.x;   // 0..767 (grid.x = 3)
    const int row = blockIdx.y;                        // 0..724
    if (col >= PS) return;
    float v = 0.0f;
    const int dr = row - POFF, dc = col - POFF;
    if ((unsigned)dr < (unsigned)NIMG && (unsigned)dc < (unsigned)NIMG)
        v = img[dr * NIMG + dc];
    pad[row * PS + col] = v;
}

// c-interval where the sample footprint can touch the nonzero data block.
// Conservative (safe to include extra; excluded samples provably contribute 0).
__device__ inline void ray_range(float ct, float st, float Bx, float By,
                                 float& lo, float& hi)
{
    lo = 0.0f; hi = 724.0f;
    if (fabsf(ct) > 1e-4f) {
        const float c1 = (104.0f - Bx) / ct, c2 = (619.0f - Bx) / ct;
        lo = fmaxf(lo, fminf(c1, c2)); hi = fminf(hi, fmaxf(c1, c2));
    } else if (Bx < 103.0f || Bx > 620.0f) { lo = 1e9f; hi = -1e9f; }
    if (fabsf(st) > 1e-4f) {
        const float c1 = (104.0f - By) / st, c2 = (619.0f - By) / st;
        lo = fmaxf(lo, fminf(c1, c2)); hi = fminf(hi, fmaxf(c1, c2));
    } else if (By < 103.0f || By > 620.0f) { lo = 1e9f; hi = -1e9f; }
    if (hi < lo) { lo = 1e9f; hi = -1e9f; }   // normalize empty
}

// Branch-free bilinear sample of padded image; exact: out-of-array samples
// redirect to idx 0 whose 4 taps are all zero => contribution 0.
__device__ inline float sample_pad(const float* __restrict__ pad,
                                   float xr, float yr)
{
    const float fx = floorf(xr), fy = floorf(yr);
    const float ax = xr - fx,  ay = yr - fy;
    const int x0 = (int)fx, y0 = (int)fy;
    const bool v = ((unsigned)x0 < 724u) && ((unsigned)y0 < 724u);
    const int idx = v ? (y0 * PS + x0) : 0;
    const float* p = pad + idx;
    const float Ia = p[0], Ib = p[1], Ic = p[PS], Id = p[PS + 1];
    const float top = fmaf(ax, Ib - Ia, Ia);
    const float bot = fmaf(ax, Id - Ic, Ic);
    return fmaf(ay, bot - top, top);
}

// ---------------- scheme A: near-horizontal angles (|ct| >= |st|) -----------
// One wave per (angle, r); lanes stride c => x-consecutive gathers.
__global__ __launch_bounds__(256) void radonA(const float* __restrict__ pad,
                                              const float* __restrict__ angles,
                                              float* __restrict__ out, int n_ang)
{
    const int wib = (int)(threadIdx.x >> 6);
    const int lane = (int)(threadIdx.x & 63);
    const int w = (int)blockIdx.x * 4 + wib;
    const int a = w / DIAG;
    const int r = w - a * DIAG;
    if (a >= n_ang) return;

    const float rad = -angles[a] * (PI_F / 180.0f);
    const float ct = cosf(rad), st = sinf(rad);
    if (fabsf(st) > fabsf(ct)) return;        // scheme B owns this angle

    const float dy = (float)r - HALF;
    const float Bx = HALF - HALF * ct - st * dy;
    const float By = HALF - HALF * st + ct * dy;

    float lo, hi;
    ray_range(ct, st, Bx, By, lo, hi);

    int iters = 0, clo = 0;
    if (hi >= lo) {
        clo = (int)fmaxf(0.0f, floorf(lo));
        const int chi = (int)fminf(724.0f, ceilf(hi));
        iters = (chi - clo) / 64 + 1;
        if (iters < 0) iters = 0;
    }

    float fc = (float)(clo + lane);
    float sum = 0.0f;
    for (int it = 0; it < iters; ++it) {
        const float xr = fmaf(ct, fc, Bx);
        const float yr = fmaf(st, fc, By);
        sum += sample_pad(pad, xr, yr);
        fc += 64.0f;
    }

    #pragma unroll
    for (int off = 32; off > 0; off >>= 1)
        sum += __shfl_down(sum, off);
    if (lane == 0)
        out[r * n_ang + a] = sum;
}

// ---------------- scheme B: near-vertical angles (|st| > |ct|) --------------
// Block = (angle, 64-row band). Lanes = rows (x-consecutive gathers);
// the block's 4 waves split the c-range; LDS combine.
__global__ __launch_bounds__(256) void radonB(const float* __restrict__ pad,
                                              const float* __restrict__ angles,
                                              float* __restrict__ out, int n_ang)
{
    const int a = (int)blockIdx.x;
    const int rb = (int)blockIdx.y;
    const int tid = (int)threadIdx.x;
    const int wib = tid >> 6, lane = tid & 63;

    const float rad = -angles[a] * (PI_F / 180.0f);
    const float ct = cosf(rad), st = sinf(rad);
    if (fabsf(st) <= fabsf(ct)) return;       // scheme A owns this angle

    const int r = rb * 64 + lane;
    const int rc = (r < DIAG) ? r : (DIAG - 1);
    const float dy = (float)rc - HALF;
    const float Bx = HALF - HALF * ct - st * dy;
    const float By = HALF - HALF * st + ct * dy;

    float lo, hi;
    ray_range(ct, st, Bx, By, lo, hi);

    // block-wide union of per-lane c-ranges
    __shared__ float s_lo[256], s_hi[256];
    s_lo[tid] = lo; s_hi[tid] = hi;
    __syncthreads();
    for (int s = 128; s > 0; s >>= 1) {
        if (tid < s) {
            s_lo[tid] = fminf(s_lo[tid], s_lo[tid + s]);
            s_hi[tid] = fmaxf(s_hi[tid], s_hi[tid + s]);
        }
        __syncthreads();
    }
    const float blo = s_lo[0], bhi = s_hi[0];

    float sum = 0.0f;
    if (bhi >= blo) {
        const int clo = (int)fmaxf(0.0f, floorf(blo));
        const int chi = (int)fminf(724.0f, ceilf(bhi));
        const int len = chi - clo + 1;
        if (len > 0) {
            const int L = (len + 3) >> 2;            // c-chunk per wave
            const int c0 = clo + wib * L;
            int c1 = c0 + L - 1; if (c1 > chi) c1 = chi;
            float fc = (float)c0;
            for (int c = c0; c <= c1; ++c) {
                const float xr = fmaf(ct, fc, Bx);
                const float yr = fmaf(st, fc, By);
                sum += sample_pad(pad, xr, yr);
                fc += 1.0f;
            }
        }
    }

    __shared__ float s_acc[4][64];
    s_acc[wib][lane] = sum;
    __syncthreads();
    if (tid < 64) {
        const float t = s_acc[0][tid] + s_acc[1][tid] + s_acc[2][tid] + s_acc[3][tid];
        const int rr = rb * 64 + tid;
        if (rr < DIAG)
            out[rr * n_ang + a] = t;
    }
}

extern "C" void kernel_launch(void* const* d_in, const int* in_sizes, int n_in,
                              void* d_out, int out_size, void* d_ws, size_t ws_size,
                              hipStream_t stream) {
    const float* img = (const float*)d_in[0];
    const float* angles = (const float*)d_in[1];
    float* out = (float*)d_out;
    float* pad = (float*)d_ws;                 // 725 * 736 * 4 B = 2.13 MB
    const int n_ang = in_sizes[1];

    pad_kernel<<<dim3(3, DIAG), 256, 0, stream>>>(img, pad);

    const int wavesA = n_ang * DIAG;
    radonA<<<(wavesA + 3) / 4, 256, 0, stream>>>(pad, angles, out, n_ang);

    radonB<<<dim3(n_ang, (DIAG + 63) / 64), 256, 0, stream>>>(pad, angles, out, n_ang);
}

// Round 3
// 107.399 us; speedup vs baseline: 2.0018x; 1.2772x over previous
//
#include <hip/hip_runtime.h>
#include <math.h>

#define DIAG 725
#define HALF 362.0f
#define NIMG 512
#define POFF 106          // data block offset inside padded image
#define PS   736          // padded row stride in floats (64B-aligned rows)
#define PI_F 3.14159265358979323846f

// Build padded image AND its transpose (both 725x725, stride 736, zero border).
__global__ __launch_bounds__(256) void pad_kernel(const float* __restrict__ img,
                                                  float* __restrict__ pad,
                                                  float* __restrict__ padT)
{
    const int col = blockIdx.x * 256 + threadIdx.x;   // 0..767 (grid.x = 3)
    const int row = blockIdx.y;                        // 0..724
    if (col >= PS) return;
    float v = 0.0f;
    const int dr = row - POFF, dc = col - POFF;
    if ((unsigned)dr < (unsigned)NIMG && (unsigned)dc < (unsigned)NIMG)
        v = img[dr * NIMG + dc];
    pad[row * PS + col] = v;
    if (col < DIAG) {
        if (padT) padT[col * PS + row] = v;
    }
}

// c-interval where the sample footprint can touch the nonzero data block.
__device__ inline void ray_range(float ct, float st, float Bx, float By,
                                 float& lo, float& hi)
{
    lo = 0.0f; hi = 724.0f;
    if (fabsf(ct) > 1e-4f) {
        const float c1 = (104.0f - Bx) / ct, c2 = (619.0f - Bx) / ct;
        lo = fmaxf(lo, fminf(c1, c2)); hi = fminf(hi, fmaxf(c1, c2));
    } else if (Bx < 103.0f || Bx > 620.0f) { lo = 1e9f; hi = -1e9f; }
    if (fabsf(st) > 1e-4f) {
        const float c1 = (104.0f - By) / st, c2 = (619.0f - By) / st;
        lo = fmaxf(lo, fminf(c1, c2)); hi = fminf(hi, fmaxf(c1, c2));
    } else if (By < 103.0f || By > 620.0f) { lo = 1e9f; hi = -1e9f; }
    if (hi < lo) { lo = 1e9f; hi = -1e9f; }
}

// Branch-free bilinear; X = fast (column) coord, Y = slow (row) coord.
// Out-of-array samples redirect to idx 0 (all-zero taps => contributes 0).
__device__ inline float sample_img(const float* __restrict__ p0,
                                   float X, float Y)
{
    const float fx = floorf(X), fy = floorf(Y);
    const float ax = X - fx,  ay = Y - fy;
    const int x0 = (int)fx, y0 = (int)fy;
    const bool v = ((unsigned)x0 < 724u) && ((unsigned)y0 < 724u);
    const int idx = v ? (y0 * PS + x0) : 0;
    const float* p = p0 + idx;
    const float Ia = p[0], Ib = p[1], Ic = p[PS], Id = p[PS + 1];
    const float top = fmaf(ax, Ib - Ia, Ia);
    const float bot = fmaf(ax, Id - Ic, Ic);
    return fmaf(ay, bot - top, top);
}

// Unified: one wave per (angle a, sinogram row r); lanes stride c.
// Near-vertical angles sample the TRANSPOSED image with coords swapped
// (bilinear is transpose-symmetric) so the fast coordinate is contiguous.
__global__ __launch_bounds__(256) void radon_uni(const float* __restrict__ pad,
                                                 const float* __restrict__ padT,
                                                 const float* __restrict__ angles,
                                                 float* __restrict__ out, int n_ang)
{
    const int wib = (int)(threadIdx.x >> 6);
    const int lane = (int)(threadIdx.x & 63);
    const int w = (int)blockIdx.x * 4 + wib;
    const int a = w / DIAG;
    const int r = w - a * DIAG;
    if (a >= n_ang) return;

    const float rad = -angles[a] * (PI_F / 180.0f);
    const float ct = cosf(rad), st = sinf(rad);

    const float dy = (float)r - HALF;
    const float Bx = HALF - HALF * ct - st * dy;   // x(c) = ct*c + Bx
    const float By = HALF - HALF * st + ct * dy;   // y(c) = st*c + By

    float lo, hi;
    ray_range(ct, st, Bx, By, lo, hi);

    int iters = 0, clo = 0;
    if (hi >= lo) {
        clo = (int)fmaxf(0.0f, floorf(lo));
        const int chi = (int)fminf(724.0f, ceilf(hi));
        iters = (chi - clo) / 64 + 1;
        if (iters < 0) iters = 0;
    }

    // Choose frame so the fast (column) coordinate has the larger |step|.
    const bool useT = (fabsf(st) > fabsf(ct)) && (padT != nullptr);
    const float* imgp = useT ? padT : pad;
    const float cF = useT ? st : ct;   // fast-coord step per c
    const float cS = useT ? ct : st;   // slow-coord step per c
    const float bF = useT ? By : Bx;
    const float bS = useT ? Bx : By;

    float fc = (float)(clo + lane);
    float s0 = 0.0f, s1 = 0.0f;
    int it = 0;
    for (; it + 1 < iters; it += 2) {
        s0 += sample_img(imgp, fmaf(cF, fc, bF),        fmaf(cS, fc, bS));
        s1 += sample_img(imgp, fmaf(cF, fc + 64.0f, bF), fmaf(cS, fc + 64.0f, bS));
        fc += 128.0f;
    }
    if (it < iters)
        s0 += sample_img(imgp, fmaf(cF, fc, bF), fmaf(cS, fc, bS));

    float sum = s0 + s1;
    #pragma unroll
    for (int off = 32; off > 0; off >>= 1)
        sum += __shfl_down(sum, off);
    if (lane == 0)
        out[r * n_ang + a] = sum;
}

extern "C" void kernel_launch(void* const* d_in, const int* in_sizes, int n_in,
                              void* d_out, int out_size, void* d_ws, size_t ws_size,
                              hipStream_t stream) {
    const float* img = (const float*)d_in[0];
    const float* angles = (const float*)d_in[1];
    float* out = (float*)d_out;
    const int n_ang = in_sizes[1];

    const size_t img_f = (size_t)DIAG * PS;            // floats per image
    float* pad = (float*)d_ws;
    float* padT = (ws_size >= 2 * img_f * sizeof(float)) ? pad + img_f : nullptr;

    pad_kernel<<<dim3(3, DIAG), 256, 0, stream>>>(img, pad, padT);

    const int waves = n_ang * DIAG;
    radon_uni<<<(waves + 3) / 4, 256, 0, stream>>>(pad, padT, angles, out, n_ang);
}